// Round 4
// baseline (356.865 us; speedup 1.0000x reference)
//
#include <hip/hip_runtime.h>
#include <hip/hip_bf16.h>
#include <cmath>

#define BN_EPS 1e-6f
typedef unsigned int u32;
typedef __attribute__((ext_vector_type(8))) short short8;   // 8 bf16 (4 VGPRs)
typedef __attribute__((ext_vector_type(4))) float f32x4;    // MFMA accum

constexpr int B_    = 4;
constexpr int N_    = 16384;
constexpr int K_    = 16;
constexpr int C_IMG = 54;
constexpr int C1    = 64;
constexpr int CO    = 32;
constexpr int C2    = 70;
constexpr int NT    = 16;     // n per block
constexpr int POS   = 256;    // positions (n,k) per block; row index = n*16+k
constexpr int XSTR  = 34;     // x_lds row stride (dwords); even -> 8B-aligned b64 reads
constexpr int PPAD  = 76;
constexpr int PBSTR = 50;     // pooled_bf row stride in u32 (48 data + 2 pad)
constexpr int NK    = N_ * K_;

__device__ inline u32 pkbf(float a, float b) {      // pack 2 fp32 -> 2 bf16 (RNE)
    union { __hip_bfloat162 h; u32 u; } cv;
    cv.h = __float22bfloat162_rn(make_float2(a, b));
    return cv.u;
}
__device__ inline float bf2f(unsigned short s) {    // bf16 bits -> fp32
    union { u32 u; float f; } cv; cv.u = ((u32)s) << 16; return cv.f;
}
// column swizzle: bijection on [0,32) per row, preserves aligned-4 contiguity
__device__ inline int SW(int pos) { return ((pos >> 4) & 7) << 2; }

__global__ __launch_bounds__(256, 4) void pif_mfma_kernel(
    const float* __restrict__ points, const float* __restrict__ imgf,
    const float* __restrict__ dist,   const int*   __restrict__ idx,
    const float* __restrict__ w1, const float* __restrict__ b1,
    const float* __restrict__ g1, const float* __restrict__ be1,
    const float* __restrict__ m1, const float* __restrict__ v1,
    const float* __restrict__ w2, const float* __restrict__ b2,
    const float* __restrict__ g2, const float* __restrict__ be2,
    const float* __restrict__ m2, const float* __restrict__ v2,
    float* __restrict__ out)
{
    __shared__ u32   x_lds[POS * XSTR];     // 34816 B; later aliased for pooled_bf hi/lo
    __shared__ float pooled[NT][PPAD];      //  4864 B (total 39680 -> 4 blocks/CU)

    const int t   = threadIdx.x;
    const int tpb = N_ / NT;
    const int b   = blockIdx.x / tpb;
    const int n0  = (blockIdx.x % tpb) * NT;
    const int k   = t & 15, ln = t >> 4, n = n0 + ln;
    const int w = t >> 6, lane = t & 63, m16 = lane & 15, quad = lane >> 4;

    // ---------------- Phase A1: geometry -> X rows (cols 0..4, swizzled) ----
    const int   base_nk = (b * N_ + n) * K_ + k;
    const int   j  = idx[base_nk];
    const float dv = dist[base_nk];
    const int   pb = (b * N_ + n) * 3;
    const float px = points[pb], py = points[pb + 1], pz = points[pb + 2];
    const int   qb = (b * N_ + j) * 3;
    const float qx = points[qb], qy = points[qb + 1], qz = points[qb + 2];

    {
        u32* row = &x_lds[t * XSTR];
        const int s = SW(t);
        row[0 ^ s] = pkbf(px, py);
        row[1 ^ s] = pkbf(pz, qx);
        row[2 ^ s] = pkbf(qy, qz);
        row[3 ^ s] = pkbf(px - qx, py - qy);
        row[4 ^ s] = pkbf(pz - qz, dv);
    }

    // ---------------- Phase A2: imgf float4 loads -> X rows (cols 5..31) ----
    // lane covers (nn = (t>>2)&15, q = t&3); wave-uniform channel pair pp.
    {
        const int nn = (t >> 2) & 15, q = t & 3;
        const int swn = ((nn & 7) << 2);
        const float* bbase = imgf + (size_t)b * C_IMG * NK + (n0 + nn) * K_ + 4 * q;
        #pragma unroll
        for (int it = 0; it < 7; ++it) {
            const int pp = w + 4 * it;            // channel pair index 0..26
            if (pp < 27) {
                const float4 L0 = *(const float4*)(bbase + (size_t)(2 * pp)     * NK);
                const float4 L1 = *(const float4*)(bbase + (size_t)(2 * pp + 1) * NK);
                const int col = (5 + pp) ^ swn;
                u32* r0 = &x_lds[(nn * 16 + 4 * q) * XSTR + col];
                r0[0 * XSTR] = pkbf(L0.x, L1.x);
                r0[1 * XSTR] = pkbf(L0.y, L1.y);
                r0[2 * XSTR] = pkbf(L0.z, L1.z);
                r0[3 * XSTR] = pkbf(L0.w, L1.w);
            }
        }
    }

    // ---------------- conv1 B-frags + BN1 constants (all waves) -------------
    short8 bfrag[2][2];
    float  inv1v[2], add1v[2];
    #pragma unroll
    for (int ot = 0; ot < 2; ++ot) {
        const int o = ot * 16 + m16;
        #pragma unroll
        for (int kc = 0; kc < 2; ++kc) {
            const float* wr = w1 + o * C1 + kc * 32 + quad * 8;
            union { u32 u[4]; short8 v; } bf;
            bf.u[0] = pkbf(wr[0], wr[1]); bf.u[1] = pkbf(wr[2], wr[3]);
            bf.u[2] = pkbf(wr[4], wr[5]); bf.u[3] = pkbf(wr[6], wr[7]);
            bfrag[ot][kc] = bf.v;
        }
        const float iv = g1[o] * rsqrtf(v1[o] + BN_EPS);
        inv1v[ot] = iv;
        add1v[ot] = be1[o] - m1[o] * iv + b1[o] * iv;
    }

    // ---------------- conv2 B-frags (waves 0,1 only): bf16 of iv2*w2 --------
    short8 w2frag[3];
    float  add2 = 0.f;
    if (w < 2) {
        const int o = w * 16 + m16;
        const float iv2 = g2[o] * rsqrtf(v2[o] + BN_EPS);
        add2 = be2[o] - m2[o] * iv2 + b2[o] * iv2;
        #pragma unroll
        for (int kc = 0; kc < 3; ++kc) {
            float wv[8];
            #pragma unroll
            for (int jj = 0; jj < 8; ++jj) {
                const int c = kc * 32 + quad * 8 + jj;
                wv[jj] = (c < C2) ? iv2 * w2[o * C2 + c] : 0.f;
            }
            union { u32 u[4]; short8 v; } bf;
            bf.u[0] = pkbf(wv[0], wv[1]); bf.u[1] = pkbf(wv[2], wv[3]);
            bf.u[2] = pkbf(wv[4], wv[5]); bf.u[3] = pkbf(wv[6], wv[7]);
            w2frag[kc] = bf.v;
        }
    }

    // ep channels of pooled (max == mean == value)
    if (t < 48) {
        const int nn = t & 15, jj = t >> 4;
        const float v = points[(b * N_ + n0 + nn) * 3 + jj];
        pooled[nn][32 + jj] = v;
        pooled[nn][67 + jj] = v;
    }

    __syncthreads();

    // ---------------- conv1 MFMA ----------------
    f32x4 acc[4][2];
    #pragma unroll
    for (int mt = 0; mt < 4; ++mt)
        #pragma unroll
        for (int ot = 0; ot < 2; ++ot)
            acc[mt][ot] = (f32x4){0.f, 0.f, 0.f, 0.f};

    #pragma unroll
    for (int mt = 0; mt < 4; ++mt) {
        const int posr = w * 64 + mt * 16 + m16;
        const int s    = ((w * 4 + mt) & 7) << 2;
        #pragma unroll
        for (int kc = 0; kc < 2; ++kc) {
            const int colb = (kc * 16 + quad * 4) ^ s;     // aligned-4 preserved
            const u32* r2 = &x_lds[posr * XSTR + colb];
            uint2 a0 = *(const uint2*)r2;
            uint2 a1 = *(const uint2*)(r2 + 2);
            union { u32 u[4]; short8 v; } af;
            af.u[0] = a0.x; af.u[1] = a0.y; af.u[2] = a1.x; af.u[3] = a1.y;
            acc[mt][0] = __builtin_amdgcn_mfma_f32_16x16x32_bf16(af.v, bfrag[0][kc], acc[mt][0], 0, 0, 0);
            acc[mt][1] = __builtin_amdgcn_mfma_f32_16x16x32_bf16(af.v, bfrag[1][kc], acc[mt][1], 0, 0, 0);
        }
    }

    // BN1 + ReLU + pool over k (within mtile: D row quad*4+reg = k)
    #pragma unroll
    for (int mt = 0; mt < 4; ++mt) {
        #pragma unroll
        for (int ot = 0; ot < 2; ++ot) {
            float mx = 0.f, sm = 0.f;
            #pragma unroll
            for (int r = 0; r < 4; ++r) {
                float hv = fmaf(acc[mt][ot][r], inv1v[ot], add1v[ot]);
                hv = fmaxf(hv, 0.f);
                mx = fmaxf(mx, hv);
                sm += hv;
            }
            mx = fmaxf(mx, __shfl_xor(mx, 16));
            mx = fmaxf(mx, __shfl_xor(mx, 32));
            sm += __shfl_xor(sm, 16);
            sm += __shfl_xor(sm, 32);
            if (quad == 0) {
                const int nn = w * 4 + mt;
                pooled[nn][ot * 16 + m16]      = mx;
                pooled[nn][35 + ot * 16 + m16] = sm * (1.f / 16.f);
            }
        }
    }
    __syncthreads();   // conv1 A-reads done AND pooled complete -> can alias x_lds

    // ---------------- repack pooled -> bf16 hi/lo A-operand (aliased) -------
    u32* pbf_hi = &x_lds[0];                 // [NT][PBSTR], 800 u32
    u32* pbf_lo = &x_lds[NT * PBSTR];        // another 800 u32
    {
        const int nn = t >> 4, j0 = t & 15;
        #pragma unroll
        for (int r = 0; r < 3; ++r) {
            const int jj = j0 + 16 * r;      // u32 col 0..47 (channels 2jj, 2jj+1; >=70 -> 0)
            const int c0 = 2 * jj, c1 = 2 * jj + 1;
            const float v0 = (c0 < C2) ? pooled[nn][c0] : 0.f;
            const float v1_ = (c1 < C2) ? pooled[nn][c1] : 0.f;
            const u32 hi = pkbf(v0, v1_);
            const float r0 = v0 - bf2f((unsigned short)(hi & 0xffff));
            const float r1 = v1_ - bf2f((unsigned short)(hi >> 16));
            pbf_hi[nn * PBSTR + jj] = hi;
            pbf_lo[nn * PBSTR + jj] = pkbf(r0, r1);
        }
    }
    __syncthreads();

    // ---------------- conv2 MFMA (waves 0,1), hi/lo split -------------------
    if (w < 2) {
        f32x4 d = (f32x4){0.f, 0.f, 0.f, 0.f};
        #pragma unroll
        for (int half = 0; half < 2; ++half) {
            const u32* pb_ = half ? pbf_lo : pbf_hi;
            #pragma unroll
            for (int kc = 0; kc < 3; ++kc) {
                const u32* r2 = &pb_[m16 * PBSTR + kc * 16 + quad * 4];
                uint2 a0 = *(const uint2*)r2;
                uint2 a1 = *(const uint2*)(r2 + 2);
                union { u32 u[4]; short8 v; } af;
                af.u[0] = a0.x; af.u[1] = a0.y; af.u[2] = a1.x; af.u[3] = a1.y;
                d = __builtin_amdgcn_mfma_f32_16x16x32_bf16(af.v, w2frag[kc], d, 0, 0, 0);
            }
        }
        // D: col=lane&15 -> o (this wave's ot = w), row=quad*4+reg -> n
        const int o = w * 16 + m16;
        f32x4 ov;
        #pragma unroll
        for (int r = 0; r < 4; ++r) ov[r] = fmaxf(d[r] + add2, 0.f);
        float4* dst = (float4*)&out[(size_t)(b * CO + o) * N_ + n0 + quad * 4];
        *dst = make_float4(ov[0], ov[1], ov[2], ov[3]);
    }
}

extern "C" void kernel_launch(void* const* d_in, const int* in_sizes, int n_in,
                              void* d_out, int out_size, void* d_ws, size_t ws_size,
                              hipStream_t stream) {
    const float* points = (const float*)d_in[0];
    const float* imgf   = (const float*)d_in[1];
    const float* dist   = (const float*)d_in[2];
    const int*   idx    = (const int*)  d_in[3];
    const float* w1     = (const float*)d_in[4];
    const float* b1     = (const float*)d_in[5];
    const float* g1     = (const float*)d_in[6];
    const float* be1    = (const float*)d_in[7];
    const float* m1     = (const float*)d_in[8];
    const float* v1     = (const float*)d_in[9];
    const float* w2     = (const float*)d_in[10];
    const float* b2     = (const float*)d_in[11];
    const float* g2     = (const float*)d_in[12];
    const float* be2    = (const float*)d_in[13];
    const float* m2     = (const float*)d_in[14];
    const float* v2     = (const float*)d_in[15];
    float* out          = (float*)d_out;

    const int blocks = B_ * (N_ / NT);       // 4096
    pif_mfma_kernel<<<blocks, 256, 0, stream>>>(
        points, imgf, dist, idx,
        w1, b1, g1, be1, m1, v1,
        w2, b2, g2, be2, m2, v2, out);
}